// Round 19
// baseline (354.934 us; speedup 1.0000x reference)
//
#include <hip/hip_runtime.h>
#include <hip/hip_bf16.h>
#include <math.h>

#define BB 2
#define SS 1024
#define DD 1024
#define FF 4096
#define HH 16
#define EE 8
#define MM (BB*SS)
#define MAX_TILES 24
#define MAX_TILES2 40

typedef __attribute__((ext_vector_type(8))) short bf16x8;
typedef __attribute__((ext_vector_type(8))) short s16x8;
typedef __attribute__((ext_vector_type(4))) float f32x4;

#define OFF_WQH  ((size_t)100663296)
#define OFF_WQL  ((size_t)106954752)
#define OFF_WOH  ((size_t)113246208)
#define OFF_WOL  ((size_t)115343360)
#define OFF_H1H  ((size_t)117440512)
#define OFF_H1L  ((size_t)121634816)
#define OFF_QKV  ((size_t)125829120)
#define OFF_OH   ((size_t)150994944)
#define OFF_OL   ((size_t)155189248)
#define OFF_X2   ((size_t)159383552)
#define OFF_H2B  ((size_t)167772160)
#define OFF_ACT  ((size_t)171966464)
#define OFF_GATE ((size_t)180879360)
#define OFF_EID  ((size_t)180887552)
#define OFF_PERM ((size_t)180895744)
#define OFF_CNT  ((size_t)180903936)
#define OFF_FILL ((size_t)180903968)
#define OFF_NT   ((size_t)180904000)
#define OFF_TE   ((size_t)180904192)
#define OFF_TS   ((size_t)180904320)
#define OFF_TR   ((size_t)180904448)
#define OFF_TE2  ((size_t)180904576)
#define OFF_TS2  ((size_t)180904768)
#define OFF_TR2  ((size_t)180904960)
#define OFF_NT2  ((size_t)180905152)
#define OFF_KSH  OFF_WQH
#define OFF_KSL  (OFF_WQH + 4194304)
#define OFF_VTH  OFF_H1H
#define OFF_VTL  OFF_H1L

__device__ __forceinline__ void gload16(const void* g, void* l) {
    __builtin_amdgcn_global_load_lds(
        (const __attribute__((address_space(1))) unsigned int*)g,
        (__attribute__((address_space(3))) unsigned int*)l, 16, 0, 0);
}

__device__ __forceinline__ short bfh(float v) {
    __hip_bfloat16 h = __float2bfloat16(v);
    return *(short*)&h;
}
__device__ __forceinline__ float bf2f(short s) {
    __hip_bfloat16 h = *(__hip_bfloat16*)&s;
    return __bfloat162float(h);
}

__device__ __forceinline__ void split_write(float v, __hip_bfloat16* hp, __hip_bfloat16* lp, size_t idx) {
    __hip_bfloat16 h = __float2bfloat16(v);
    hp[idx] = h;
    lp[idx] = __float2bfloat16(v - __bfloat162float(h));
}

// ---------------- phase-0 ----------------
__global__ void k_phase0(const float* __restrict__ x, const float* __restrict__ ln1w,
                         const float* __restrict__ ln1b,
                         __hip_bfloat16* __restrict__ h1H, __hip_bfloat16* __restrict__ h1L,
                         const float* __restrict__ w_qkv, __hip_bfloat16* __restrict__ wqH,
                         __hip_bfloat16* __restrict__ wqL,
                         const float* __restrict__ w_out, __hip_bfloat16* __restrict__ woH,
                         __hip_bfloat16* __restrict__ woL) {
    __shared__ __align__(16) float smem[1032];
    int bid = blockIdx.x, t = threadIdx.x;
    if (bid < 2048) {
        int m = bid, s = m & (SS - 1);
        float* row = smem;
        float* red = smem + 1024;
        const float* xp = x + (size_t)m * DD;
        float sum = 0.f, sumsq = 0.f;
#pragma unroll
        for (int l = 0; l < 4; ++l) {
            int i = t + l * 256;
            float v = xp[i];
            row[i] = v;
            sum += v; sumsq += v * v;
        }
#pragma unroll
        for (int off = 32; off; off >>= 1) {
            sum   += __shfl_xor(sum, off);
            sumsq += __shfl_xor(sumsq, off);
        }
        int wid = t >> 6, lane = t & 63;
        if (lane == 0) { red[wid] = sum; red[4 + wid] = sumsq; }
        __syncthreads();
        sum   = red[0] + red[1] + red[2] + red[3];
        sumsq = red[4] + red[5] + red[6] + red[7];
        float mean = sum * (1.f / DD);
        float var  = sumsq * (1.f / DD) - mean * mean;
        float rstd = rsqrtf(var + 1e-5f);
        size_t base = (size_t)m * DD;
        const float kln = logf(10000.f) / 512.f;
#pragma unroll
        for (int l = 0; l < 2; ++l) {
            int i = t + l * 256;
            float n1 = (row[i]       - mean) * rstd * ln1w[i]       + ln1b[i];
            float n2 = (row[i + 512] - mean) * rstd * ln1w[i + 512] + ln1b[i + 512];
            float inv = expf(-(float)i * kln);
            float ang = (float)s * inv;
            float c = cosf(ang), sn = sinf(ang);
            split_write(n1 * c - n2 * sn,  h1H, h1L, base + i);
            split_write(n1 * sn + n2 * c, h1H, h1L, base + i + 512);
        }
    } else if (bid < 5120) {
        int idx = (bid - 2048) * 256 + t;
        float4 v = ((const float4*)w_qkv)[idx];
        split_write(v.x, wqH, wqL, (size_t)idx * 4 + 0);
        split_write(v.y, wqH, wqL, (size_t)idx * 4 + 1);
        split_write(v.z, wqH, wqL, (size_t)idx * 4 + 2);
        split_write(v.w, wqH, wqL, (size_t)idx * 4 + 3);
    } else {
        int idx = (bid - 5120) * 256 + t;
        float4 v = ((const float4*)w_out)[idx];
        split_write(v.x, woH, woL, (size_t)idx * 4 + 0);
        split_write(v.y, woH, woL, (size_t)idx * 4 + 1);
        split_write(v.z, woH, woL, (size_t)idx * 4 + 2);
        split_write(v.w, woH, woL, (size_t)idx * 4 + 3);
    }
}

// ---------------- qkv split GEMM ----------------
__global__ void k_qkv(const __hip_bfloat16* __restrict__ Ah, const __hip_bfloat16* __restrict__ Al,
                      const __hip_bfloat16* __restrict__ Bh, const __hip_bfloat16* __restrict__ Bl,
                      const float* __restrict__ bias, float* __restrict__ Cf) {
    __shared__ __align__(16) short AsH[64 * 32];
    __shared__ __align__(16) short AsL[64 * 32];
    __shared__ __align__(16) short BsH[128 * 32];
    __shared__ __align__(16) short BsL[128 * 32];
    const int N = 3072, K = DD;
    int bid = blockIdx.x;
    int xcd = bid & 7, idx = bid >> 3;
    int nt = xcd + (idx >> 5) * 8;
    int mt = idx & 31;
    int m0 = mt * 64, n0 = nt * 128;
    const int t = threadIdx.x;
    const int w = t >> 6, lane = t & 63;
    const int sid = w * 64 + lane;
    const int g = lane >> 4, r16 = lane & 15;

    f32x4 acc[4][2] = {};

    for (int k0 = 0; k0 < K; k0 += 32) {
        {
            int rrow = sid >> 2, sl = sid & 3;
            int slog = sl ^ ((rrow >> 1) & 3);
            size_t lbase = (size_t)(w * 64) * 8;
            size_t gaoff = (size_t)(m0 + rrow) * K + k0 + slog * 8;
            gload16(Ah + gaoff, &AsH[lbase]);
            gload16(Al + gaoff, &AsL[lbase]);
        }
#pragma unroll
        for (int j = 0; j < 2; ++j) {
            int id = j * 256 + sid;
            int rrow = id >> 2, sl = id & 3;
            int slog = sl ^ ((rrow >> 1) & 3);
            size_t lbase = (size_t)(j * 256 + w * 64) * 8;
            size_t gboff = (size_t)(n0 + rrow) * K + k0 + slog * 8;
            gload16(Bh + gboff, &BsH[lbase]);
            gload16(Bl + gboff, &BsL[lbase]);
        }
        __syncthreads();
        bf16x8 ah[4], al[4], bh[2], bl[2];
#pragma unroll
        for (int i = 0; i < 4; ++i) {
            int ra = i * 16 + r16;
            int pa = g ^ ((ra >> 1) & 3);
            ah[i] = *(const bf16x8*)&AsH[ra * 32 + pa * 8];
            al[i] = *(const bf16x8*)&AsL[ra * 32 + pa * 8];
        }
#pragma unroll
        for (int n = 0; n < 2; ++n) {
            int rb = w * 32 + n * 16 + r16;
            int pb = g ^ ((rb >> 1) & 3);
            bh[n] = *(const bf16x8*)&BsH[rb * 32 + pb * 8];
            bl[n] = *(const bf16x8*)&BsL[rb * 32 + pb * 8];
        }
#pragma unroll
        for (int i = 0; i < 4; ++i)
#pragma unroll
            for (int n = 0; n < 2; ++n) {
                acc[i][n] = __builtin_amdgcn_mfma_f32_16x16x32_bf16(ah[i], bh[n], acc[i][n], 0, 0, 0);
                acc[i][n] = __builtin_amdgcn_mfma_f32_16x16x32_bf16(ah[i], bl[n], acc[i][n], 0, 0, 0);
                acc[i][n] = __builtin_amdgcn_mfma_f32_16x16x32_bf16(al[i], bh[n], acc[i][n], 0, 0, 0);
            }
        __syncthreads();
    }

#pragma unroll
    for (int i = 0; i < 4; ++i) {
#pragma unroll
        for (int n = 0; n < 2; ++n) {
            int col = n0 + w * 32 + n * 16 + r16;
#pragma unroll
            for (int q = 0; q < 4; ++q) {
                int r = m0 + i * 16 + g * 4 + q;
                Cf[(size_t)r * N + col] = acc[i][n][q] + bias[col];
            }
        }
    }
}

// ---------------- out-proj split GEMM ----------------
__global__ void k_oproj64(const __hip_bfloat16* __restrict__ Ah, const __hip_bfloat16* __restrict__ Al,
                          const __hip_bfloat16* __restrict__ Bh, const __hip_bfloat16* __restrict__ Bl,
                          const float* __restrict__ bias, const float* __restrict__ addsrc,
                          float* __restrict__ Cf, int* __restrict__ zero17) {
    __shared__ __align__(16) short AsH[64 * 32];
    __shared__ __align__(16) short AsL[64 * 32];
    __shared__ __align__(16) short BsH[128 * 32];
    __shared__ __align__(16) short BsL[128 * 32];
    const int N = DD, K = DD;
    int bid = blockIdx.x;
    int m0 = (bid >> 3) * 64, n0 = (bid & 7) * 128;
    const int t = threadIdx.x;
    if (bid == 0 && t < 17) zero17[t] = 0;
    const int w = t >> 6, lane = t & 63;
    const int sid = w * 64 + lane;
    const int g = lane >> 4, r16 = lane & 15;

    f32x4 acc[4][2] = {};

    for (int k0 = 0; k0 < K; k0 += 32) {
        {
            int rrow = sid >> 2, sl = sid & 3;
            int slog = sl ^ ((rrow >> 1) & 3);
            size_t lbase = (size_t)(w * 64) * 8;
            size_t gaoff = (size_t)(m0 + rrow) * K + k0 + slog * 8;
            gload16(Ah + gaoff, &AsH[lbase]);
            gload16(Al + gaoff, &AsL[lbase]);
        }
#pragma unroll
        for (int j = 0; j < 2; ++j) {
            int id = j * 256 + sid;
            int rrow = id >> 2, sl = id & 3;
            int slog = sl ^ ((rrow >> 1) & 3);
            size_t lbase = (size_t)(j * 256 + w * 64) * 8;
            size_t gboff = (size_t)(n0 + rrow) * K + k0 + slog * 8;
            gload16(Bh + gboff, &BsH[lbase]);
            gload16(Bl + gboff, &BsL[lbase]);
        }
        __syncthreads();
        bf16x8 ah[4], al[4], bh[2], bl[2];
#pragma unroll
        for (int i = 0; i < 4; ++i) {
            int ra = i * 16 + r16;
            int pa = g ^ ((ra >> 1) & 3);
            ah[i] = *(const bf16x8*)&AsH[ra * 32 + pa * 8];
            al[i] = *(const bf16x8*)&AsL[ra * 32 + pa * 8];
        }
#pragma unroll
        for (int n = 0; n < 2; ++n) {
            int rb = w * 32 + n * 16 + r16;
            int pb = g ^ ((rb >> 1) & 3);
            bh[n] = *(const bf16x8*)&BsH[rb * 32 + pb * 8];
            bl[n] = *(const bf16x8*)&BsL[rb * 32 + pb * 8];
        }
#pragma unroll
        for (int i = 0; i < 4; ++i)
#pragma unroll
            for (int n = 0; n < 2; ++n) {
                acc[i][n] = __builtin_amdgcn_mfma_f32_16x16x32_bf16(ah[i], bh[n], acc[i][n], 0, 0, 0);
                acc[i][n] = __builtin_amdgcn_mfma_f32_16x16x32_bf16(ah[i], bl[n], acc[i][n], 0, 0, 0);
                acc[i][n] = __builtin_amdgcn_mfma_f32_16x16x32_bf16(al[i], bh[n], acc[i][n], 0, 0, 0);
            }
        __syncthreads();
    }

#pragma unroll
    for (int i = 0; i < 4; ++i) {
#pragma unroll
        for (int n = 0; n < 2; ++n) {
            int col = n0 + w * 32 + n * 16 + r16;
#pragma unroll
            for (int q = 0; q < 4; ++q) {
                int r = m0 + i * 16 + g * 4 + q;
                Cf[(size_t)r * N + col] =
                    acc[i][n][q] + bias[col] + addsrc[(size_t)r * N + col];
            }
        }
    }
}

// ---------------- MoE up-proj: BM=128 (24-tile list), BK=64 (two 32-k panels),
// direct f32 wi, padded panels, register-prefetched staging ----------------
#define LDB 36
__global__ void k_moe_up(const __hip_bfloat16* __restrict__ A,
                         const float* __restrict__ wi,
                         __hip_bfloat16* __restrict__ act,
                         const int* __restrict__ perm,
                         const int* __restrict__ te, const int* __restrict__ ts,
                         const int* __restrict__ tr, const int* __restrict__ ntl) {
    __shared__ __align__(16) short As[2][128 * 32];
    __shared__ __align__(16) short Bs[2][128 * LDB];
    __shared__ int permS[128];
    int tile = blockIdx.y;
    if (tile >= *ntl) return;
    int e = te[tile], rs = ts[tile], rows = tr[tile];
    const int t = threadIdx.x;
    if (t < 128) permS[t] = (t < rows) ? perm[rs + t] : 0;
    __syncthreads();
    int c0 = blockIdx.x * 64;
    const int w = t >> 6, lane = t & 63;
    const int wr = w >> 1, wc = w & 1;
    const int sid = w * 64 + lane;
    const int g = lane >> 4, r16 = lane & 15;

    const float* Bp = wi + (size_t)e * DD * FF;

    // B-staging constants (r17-proven): cc covers 64 a-cols + 64 g-cols
    const int cc = t & 127, kp0 = t >> 7;
    const int Lc = cc & 63, T = cc >> 6;
    const int qidx = (Lc >> 5) * 4 + ((Lc >> 4) & 1) * 2 + T;
    const int rbb = qidx * 16 + (Lc & 15);
    const size_t coloff = (size_t)(c0 + T * 2048 + Lc);

    f32x4 acc[4][4] = {};

    // prologue: prefetch k0=0 (64 k = 32 f32 per thread across both panels)
    float vcur[32];
#pragma unroll
    for (int pass = 0; pass < 16; ++pass) {
        int kpg = pass * 2 + kp0;                       // 0..31, k = 2*kpg
        const float* wp = Bp + (size_t)(kpg * 2) * FF + coloff;
        vcur[pass * 2]     = wp[0];
        vcur[pass * 2 + 1] = wp[FF];
    }

    for (int k0 = 0; k0 < DD; k0 += 64) {
        // A: two 32-k panels x 128 gathered rows, 2 gload passes each
#pragma unroll
        for (int p = 0; p < 2; ++p)
#pragma unroll
            for (int j = 0; j < 2; ++j) {
                int id = j * 256 + sid;
                int rrow = id >> 2, sl = id & 3;
                int slog = sl ^ ((rrow >> 1) & 3);
                size_t lbase = (size_t)(j * 256 + w * 64) * 8;
                gload16(A + (size_t)permS[rrow] * DD + k0 + p * 32 + slog * 8, &As[p][lbase]);
            }
        // B: write LDS from prefetched registers
#pragma unroll
        for (int pass = 0; pass < 16; ++pass) {
            int kpg = pass * 2 + kp0;
            int panel = kpg >> 4, kpl = kpg & 15;
            unsigned u = (unsigned)(unsigned short)bfh(vcur[pass * 2])
                       | ((unsigned)(unsigned short)bfh(vcur[pass * 2 + 1]) << 16);
            *(unsigned*)&Bs[panel][rbb * LDB + kpl * 2] = u;
        }
        __syncthreads();
        // issue next-step B loads (in flight under MFMA section)
        float vnext[32];
        if (k0 + 64 < DD) {
#pragma unroll
            for (int pass = 0; pass < 16; ++pass) {
                int kpg = pass * 2 + kp0;
                const float* wp = Bp + (size_t)(k0 + 64 + kpg * 2) * FF + coloff;
                vnext[pass * 2]     = wp[0];
                vnext[pass * 2 + 1] = wp[FF];
            }
        }
        // fragments + 32 MFMAs (16 per panel)
#pragma unroll
        for (int ks = 0; ks < 2; ++ks) {
            bf16x8 af[4], bfr[4];
#pragma unroll
            for (int i = 0; i < 4; ++i) {
                int ra = wr * 64 + i * 16 + r16;
                int pa = g ^ ((ra >> 1) & 3);
                af[i] = *(const bf16x8*)&As[ks][ra * 32 + pa * 8];
            }
#pragma unroll
            for (int n = 0; n < 4; ++n) {
                int rb = wc * 64 + n * 16 + r16;
                bfr[n] = *(const bf16x8*)&Bs[ks][rb * LDB + g * 8];
            }
#pragma unroll
            for (int i = 0; i < 4; ++i)
#pragma unroll
                for (int n = 0; n < 4; ++n)
                    acc[i][n] = __builtin_amdgcn_mfma_f32_16x16x32_bf16(af[i], bfr[n], acc[i][n], 0, 0, 0);
        }
        __syncthreads();
        if (k0 + 64 < DD) {
#pragma unroll
            for (int j = 0; j < 32; ++j) vcur[j] = vnext[j];
        }
    }

    // epilogue (r17-proven): (n=2p2, n=2p2+1) pair = (a, g) of same col
#pragma unroll
    for (int i = 0; i < 4; ++i) {
#pragma unroll
        for (int p2 = 0; p2 < 2; ++p2) {
            int col = c0 + wc * 32 + p2 * 16 + r16;
#pragma unroll
            for (int q = 0; q < 4; ++q) {
                int r = wr * 64 + i * 16 + g * 4 + q;
                if (r < rows) {
                    float a  = acc[i][2 * p2][q];
                    float gv = acc[i][2 * p2 + 1][q];
                    act[(size_t)(rs + r) * 2048 + col] =
                        __float2bfloat16((a / (1.f + expf(-a))) * gv);
                }
            }
        }
    }
}

// ---------------- MoE down-proj: 64x64 tile, BK=64 (two panels), direct f32 wo,
// padded panels, register-prefetched staging ----------------
__global__ void k_moe_dn(const __hip_bfloat16* __restrict__ A,
                         const float* __restrict__ wo,
                         const float* __restrict__ addsrc, float* __restrict__ Cf,
                         const int* __restrict__ perm,
                         const int* __restrict__ te2, const int* __restrict__ ts2,
                         const int* __restrict__ tr2, const int* __restrict__ ntl2,
                         const float* __restrict__ gate) {
    __shared__ __align__(16) short As[2][64 * 32];
    __shared__ __align__(16) short Bs[2][64 * LDB];
    __shared__ int permS[64];
    int tile = blockIdx.y;
    if (tile >= *ntl2) return;
    int e = te2[tile], rs = ts2[tile], rows = tr2[tile];
    const int t = threadIdx.x;
    if (t < 64) permS[t] = (t < rows) ? perm[rs + t] : 0;
    __syncthreads();
    int n0 = blockIdx.x * 64;
    const int w = t >> 6, lane = t & 63;
    const int g = lane >> 4, r16 = lane & 15;
    const int K = FF / 2;

    const float* Bp = wo + (size_t)e * (size_t)K * DD;
    const int cc = t & 63, kp0 = t >> 6;   // 64 cols x 4 k-pair groups

    f32x4 acc[4] = {};

    float vcur[16];
#pragma unroll
    for (int pass = 0; pass < 8; ++pass) {
        int kpg = pass * 4 + kp0;                       // 0..31
        const float* wp = Bp + (size_t)(kpg * 2) * DD + n0 + cc;
        vcur[pass * 2]     = wp[0];
        vcur[pass * 2 + 1] = wp[DD];
    }

    for (int k0 = 0; k0 < K; k0 += 64) {
#pragma unroll
        for (int j = 0; j < 2; ++j) {
            int rrow = t >> 2, sl = t & 3;
            int slog = sl ^ ((rrow >> 1) & 3);
            size_t lbase = (size_t)(w * 64) * 8;
            gload16(A + (size_t)(rs + rrow) * K + k0 + j * 32 + slog * 8, &As[j][lbase]);
        }
#pragma unroll
        for (int pass = 0; pass < 8; ++pass) {
            int kpg = pass * 4 + kp0;
            int panel = kpg >> 4, kpl = kpg & 15;
            unsigned u = (unsigned)(unsigned short)bfh(vcur[pass * 2])
                       | ((unsigned)(unsigned short)bfh(vcur[pass * 2 + 1]) << 16);
            *(unsigned*)&Bs[panel][cc * LDB + kpl * 2] = u;
        }
        __syncthreads();
        float vnext[16];
        if (k0 + 64 < K) {
#pragma unroll
            for (int pass = 0; pass < 8; ++pass) {
                int kpg = pass * 4 + kp0;
                const float* wp = Bp + (size_t)(k0 + 64 + kpg * 2) * DD + n0 + cc;
                vnext[pass * 2]     = wp[0];
                vnext[pass * 2 + 1] = wp[DD];
            }
        }
#pragma unroll
        for (int ks = 0; ks < 2; ++ks) {
            bf16x8 af[4], bfr;
#pragma unroll
            for (int i = 0; i < 4; ++i) {
                int ra = i * 16 + r16;
                int pa = g ^ ((ra >> 1) & 3);
                af[i] = *(const bf16x8*)&As[ks][ra * 32 + pa * 8];
            }
            {
                int rb = w * 16 + r16;
                bfr = *(const bf16x8*)&Bs[ks][rb * LDB + g * 8];
            }
#pragma unroll
            for (int i = 0; i < 4; ++i)
                acc[i] = __builtin_amdgcn_mfma_f32_16x16x32_bf16(af[i], bfr, acc[i], 0, 0, 0);
        }
        __syncthreads();
        if (k0 + 64 < K) {
#pragma unroll
            for (int j = 0; j < 16; ++j) vcur[j] = vnext[j];
        }
    }

#pragma unroll
    for (int i = 0; i < 4; ++i) {
        int col = n0 + w * 16 + r16;
#pragma unroll
        for (int q = 0; q < 4; ++q) {
            int r = i * 16 + g * 4 + q;
            if (r >= rows) continue;
            int tok = permS[r];
            Cf[(size_t)tok * DD + col] = addsrc[(size_t)tok * DD + col] + gate[tok] * acc[i][q];
        }
    }
}

// ---------------- attention prep ----------------
__global__ void k_prep(const float* __restrict__ qkv, short* __restrict__ KH, short* __restrict__ KL,
                       short* __restrict__ VH, short* __restrict__ VL) {
    __shared__ float tile[64][65];
    int b = blockIdx.z, h = blockIdx.y, s0 = blockIdx.x * 64;
    int t = threadIdx.x;
    int row = t >> 2, c0 = (t & 3) * 16;
    const float* kp = qkv + (size_t)(b * SS + s0 + row) * 3072 + 1024 + h * 64 + c0;
    const float* vp = kp + 1024;
    {
        size_t krow = ((size_t)(b * HH + h) * SS + s0 + row) * 64;
        int key = (s0 + row) & 7;
#pragma unroll
        for (int g2 = 0; g2 < 2; ++g2) {
            s16x8 hv, lv;
#pragma unroll
            for (int j = 0; j < 8; ++j) {
                float v = kp[g2 * 8 + j];
                short hh = bfh(v);
                hv[j] = hh; lv[j] = bfh(v - bf2f(hh));
            }
            int p = ((c0 >> 3) + g2) ^ key;
            *(s16x8*)&KH[krow + p * 8] = hv;
            *(s16x8*)&KL[krow + p * 8] = lv;
        }
    }
#pragma unroll
    for (int j = 0; j < 16; ++j) tile[row][c0 + j] = vp[j];
    __syncthreads();
    {
        int d = t >> 2, sc = (t & 3) * 16;
        size_t vrow = ((size_t)(b * HH + h) * 64 + d) * SS + s0;
        int key = d & 7;
#pragma unroll
        for (int g2 = 0; g2 < 2; ++g2) {
            s16x8 hv, lv;
#pragma unroll
            for (int j = 0; j < 8; ++j) {
                float v = tile[sc + g2 * 8 + j][d];
                short hh = bfh(v);
                hv[j] = hh; lv[j] = bfh(v - bf2f(hh));
            }
            int p = ((sc >> 3) + g2) ^ key;
            *(s16x8*)&VH[vrow + p * 8] = hv;
            *(s16x8*)&VL[vrow + p * 8] = lv;
        }
    }
}

// ---------------- MFMA flash attention ----------------
#define LDP 72
__global__ __launch_bounds__(512, 1)
void k_attn_mfma(const float* __restrict__ qkv,
                 const short* __restrict__ KH, const short* __restrict__ KL,
                 const short* __restrict__ VH, const short* __restrict__ VL,
                 __hip_bfloat16* __restrict__ ohi, __hip_bfloat16* __restrict__ olo) {
    __shared__ __align__(16) short Ks[2][64 * 64], Kl2[2][64 * 64], Vs[2][64 * 64], Vl2[2][64 * 64];
    __shared__ __align__(16) short PhS[8][16 * LDP], PlS[8][16 * LDP];
    int id = blockIdx.x;
    int xcd = id & 7, slot = id >> 3;
    int bh = xcd * 4 + (slot >> 3);
    int q0 = (slot & 7) * 128;
    int b = bh >> 4, h = bh & 15;
    int t = threadIdx.x;
    int w = t >> 6, lane = t & 63;
    int g = lane >> 4, r16 = lane & 15;
    int srow = t >> 3, sslot = t & 7;

    const size_t kbase = ((size_t)bh * SS) * 64;
    const size_t vbase = ((size_t)bh * 64) * SS;

    bf16x8 qfh[2], qfl[2];
    {
        const float* qp = qkv + (size_t)(b * SS + q0 + w * 16 + r16) * 3072 + h * 64;
#pragma unroll
        for (int ks = 0; ks < 2; ++ks) {
            float vv[8];
            *(float4*)&vv[0] = *(const float4*)(qp + ks * 32 + g * 8);
            *(float4*)&vv[4] = *(const float4*)(qp + ks * 32 + g * 8 + 4);
#pragma unroll
            for (int j = 0; j < 8; ++j) {
                float sv = vv[j] * 0.125f;
                short hh = bfh(sv);
                qfh[ks][j] = hh;
                qfl[ks][j] = bfh(sv - bf2f(hh));
            }
        }
    }

    float mrun[4], lrun[4];
    f32x4 oacc[4] = {};
#pragma unroll
    for (int q = 0; q < 4; ++q) { mrun[q] = -1e30f; lrun[q] = 0.f; }

    gload16(KH + kbase + (size_t)srow * 64 + sslot * 8, &Ks[0][w * 512]);
    gload16(KL + kbase + (size_t)srow * 64 + sslot * 8, &Kl2[0][w * 512]);
    gload16(VH + vbase + (size_t)srow * SS + sslot * 8, &Vs[0][w * 512]);
    gload16(VL + vbase + (size_t)srow * SS + sslot * 8, &Vl2[0][w * 512]);
    __syncthreads();

    int cur = 0;
    for (int k0 = 0; k0 < SS; k0 += 64) {
        if (k0 + 64 < SS) {
            int kn = k0 + 64;
            gload16(KH + kbase + (size_t)(kn + srow) * 64 + sslot * 8, &Ks[cur ^ 1][w * 512]);
            gload16(KL + kbase + (size_t)(kn + srow) * 64 + sslot * 8, &Kl2[cur ^ 1][w * 512]);
            gload16(VH + vbase + (size_t)srow * SS + kn + sslot * 8,   &Vs[cur ^ 1][w * 512]);
            gload16(VL + vbase + (size_t)srow * SS + kn + sslot * 8,   &Vl2[cur ^ 1][w * 512]);
        }

        f32x4 accs[4] = {};
#pragma unroll
        for (int ks = 0; ks < 2; ++ks) {
            bf16x8 kfh[4], kfl[4];
#pragma unroll
            for (int n = 0; n < 4; ++n) {
                int rb = n * 16 + r16;
                int p = (ks * 4 + g) ^ (r16 & 7);
                kfh[n] = *(const bf16x8*)&Ks[cur][rb * 64 + p * 8];
                kfl[n] = *(const bf16x8*)&Kl2[cur][rb * 64 + p * 8];
            }
            __builtin_amdgcn_s_setprio(1);
#pragma unroll
            for (int n = 0; n < 4; ++n) {
                accs[n] = __builtin_amdgcn_mfma_f32_16x16x32_bf16(qfh[ks], kfh[n], accs[n], 0, 0, 0);
                accs[n] = __builtin_amdgcn_mfma_f32_16x16x32_bf16(qfh[ks], kfl[n], accs[n], 0, 0, 0);
                accs[n] = __builtin_amdgcn_mfma_f32_16x16x32_bf16(qfl[ks], kfh[n], accs[n], 0, 0, 0);
            }
            __builtin_amdgcn_s_setprio(0);
        }

        float mn[4], corr[4], psum[4];
#pragma unroll
        for (int q = 0; q < 4; ++q) {
            float m = fmaxf(fmaxf(accs[0][q], accs[1][q]), fmaxf(accs[2][q], accs[3][q]));
            m = fmaxf(m, __shfl_xor(m, 1));
            m = fmaxf(m, __shfl_xor(m, 2));
            m = fmaxf(m, __shfl_xor(m, 4));
            m = fmaxf(m, __shfl_xor(m, 8));
            mn[q] = fmaxf(mrun[q], m);
            corr[q] = expf(mrun[q] - mn[q]);
            mrun[q] = mn[q];
            psum[q] = 0.f;
        }
#pragma unroll
        for (int n = 0; n < 4; ++n)
#pragma unroll
            for (int q = 0; q < 4; ++q) {
                float p = expf(accs[n][q] - mn[q]);
                psum[q] += p;
                short ph = bfh(p);
                PhS[w][(g * 4 + q) * LDP + n * 16 + r16] = ph;
                PlS[w][(g * 4 + q) * LDP + n * 16 + r16] = bfh(p - bf2f(ph));
            }
#pragma unroll
        for (int q = 0; q < 4; ++q) {
            psum[q] += __shfl_xor(psum[q], 1);
            psum[q] += __shfl_xor(psum[q], 2);
            psum[q] += __shfl_xor(psum[q], 4);
            psum[q] += __shfl_xor(psum[q], 8);
            lrun[q] = lrun[q] * corr[q] + psum[q];
#pragma unroll
            for (int n = 0; n < 4; ++n) oacc[n][q] *= corr[q];
        }

#pragma unroll
        for (int ks = 0; ks < 2; ++ks) {
            bf16x8 vfh[4], vfl[4];
#pragma unroll
            for (int n = 0; n < 4; ++n) {
                int rb = n * 16 + r16;
                int p = (ks * 4 + g) ^ (r16 & 7);
                vfh[n] = *(const bf16x8*)&Vs[cur][rb * 64 + p * 8];
                vfl[n] = *(const bf16x8*)&Vl2[cur][rb * 64 + p * 8];
            }
            bf16x8 pfh = *(const bf16x8*)&PhS[w][r16 * LDP + ks * 32 + g * 8];
            bf16x8 pfl = *(const bf16x8*)&PlS[w][r16 * LDP + ks * 32 + g * 8];
            __builtin_amdgcn_s_setprio(1);
#pragma unroll
            for (int n = 0; n < 4; ++n) {
                oacc[n] = __builtin_amdgcn_mfma_f32_16x16x32_bf16(pfh, vfh[n], oacc[n], 0, 0, 0);
                oacc[n] = __builtin_amdgcn_mfma_f32_16x16x32_bf16(pfh, vfl[n], oacc[n], 0, 0, 0);
                oacc[n] = __builtin_amdgcn_mfma_f32_16x16x32_bf16(pfl, vfh[n], oacc[n], 0, 0, 0);
            }
            __builtin_amdgcn_s_setprio(0);
        }
        __syncthreads();
        cur ^= 1;
    }

    float invl[4];
#pragma unroll
    for (int q = 0; q < 4; ++q) invl[q] = 1.f / lrun[q];
#pragma unroll
    for (int n = 0; n < 4; ++n) {
        int col = h * 64 + n * 16 + r16;
#pragma unroll
        for (int q = 0; q < 4; ++q) {
            int rowg = b * SS + q0 + w * 16 + g * 4 + q;
            split_write(oacc[n][q] * invl[q], ohi, olo, (size_t)rowg * DD + col);
        }
    }
}

// ---------------- fused LN2 + router ----------------
__global__ void k_ln2_router(const float* __restrict__ x2, const float* __restrict__ w,
                             const float* __restrict__ b, const float* __restrict__ wr,
                             __hip_bfloat16* __restrict__ h2b, float* __restrict__ logits,
                             float* __restrict__ gate, int* __restrict__ eid,
                             int* __restrict__ counts) {
    int m = blockIdx.x, t = threadIdx.x;
    __shared__ float red[8];
    __shared__ float racc[4][8];
    const float* xp = x2 + (size_t)m * DD;
    float v[4];
    float sum = 0.f, sumsq = 0.f;
#pragma unroll
    for (int l = 0; l < 4; ++l) {
        v[l] = xp[t + l * 256];
        sum += v[l]; sumsq += v[l] * v[l];
    }
#pragma unroll
    for (int off = 32; off; off >>= 1) {
        sum   += __shfl_xor(sum, off);
        sumsq += __shfl_xor(sumsq, off);
    }
    int wid = t >> 6, lane = t & 63;
    if (lane == 0) { red[wid] = sum; red[4 + wid] = sumsq; }
    __syncthreads();
    sum   = red[0] + red[1] + red[2] + red[3];
    sumsq = red[4] + red[5] + red[6] + red[7];
    float mean = sum * (1.f / DD);
    float var  = sumsq * (1.f / DD) - mean * mean;
    float rstd = rsqrtf(var + 1e-5f);
    float acc[EE] = {};
#pragma unroll
    for (int l = 0; l < 4; ++l) {
        int i = t + l * 256;
        float hv = (v[l] - mean) * rstd * w[i] + b[i];
        h2b[(size_t)m * DD + i] = __float2bfloat16(hv);
        const float* wp = wr + (size_t)i * EE;
#pragma unroll
        for (int n = 0; n < EE; ++n) acc[n] += hv * wp[n];
    }
#pragma unroll
    for (int off = 32; off; off >>= 1)
#pragma unroll
        for (int n = 0; n < EE; ++n) acc[n] += __shfl_xor(acc[n], off);
    if (lane == 0)
#pragma unroll
        for (int n = 0; n < EE; ++n) racc[wid][n] = acc[n];
    __syncthreads();
    if (t == 0) {
        float lg[EE];
#pragma unroll
        for (int n = 0; n < EE; ++n) lg[n] = racc[0][n] + racc[1][n] + racc[2][n] + racc[3][n];
        float mx = lg[0]; int best = 0;
#pragma unroll
        for (int n = 1; n < EE; ++n) if (lg[n] > mx) { mx = lg[n]; best = n; }
        float den = 0.f;
#pragma unroll
        for (int n = 0; n < EE; ++n) den += expf(lg[n] - mx);
        gate[m] = 1.f / den;
        eid[m] = best;
        atomicAdd(&counts[best], 1);
#pragma unroll
        for (int n = 0; n < EE; ++n) logits[(size_t)m * EE + n] = lg[n];
    }
}

// ---------------- routing bookkeeping ----------------
__global__ void k_offscatter(const int* __restrict__ counts,
                             int* __restrict__ te, int* __restrict__ ts, int* __restrict__ tr,
                             int* __restrict__ ntl,
                             int* __restrict__ te2, int* __restrict__ ts2, int* __restrict__ tr2,
                             int* __restrict__ ntl2,
                             const int* __restrict__ eid,
                             int* __restrict__ fill, int* __restrict__ perm) {
    __shared__ int soffs[EE];
    int t = threadIdx.x;
    if (t == 0) {
        int off = 0, nt = 0, nt2 = 0;
        for (int e = 0; e < EE; ++e) {
            soffs[e] = off;
            int c = counts[e];
            for (int t0 = 0; t0 < c; t0 += 128) {
                te[nt] = e; ts[nt] = off + t0; tr[nt] = (c - t0 < 128) ? (c - t0) : 128; ++nt;
            }
            for (int t0 = 0; t0 < c; t0 += 64) {
                te2[nt2] = e; ts2[nt2] = off + t0; tr2[nt2] = (c - t0 < 64) ? (c - t0) : 64; ++nt2;
            }
            off += c;
        }
        *ntl = nt;
        *ntl2 = nt2;
    }
    __syncthreads();
#pragma unroll
    for (int tok = t; tok < MM; tok += 1024) {
        int e = eid[tok];
        int pos = soffs[e] + atomicAdd(&fill[e], 1);
        perm[pos] = tok;
    }
}

// ---------------- launch ----------------
extern "C" void kernel_launch(void* const* d_in, const int* in_sizes, int n_in,
                              void* d_out, int out_size, void* d_ws, size_t ws_size,
                              hipStream_t stream) {
    const float* x     = (const float*)d_in[0];
    const float* ln1w  = (const float*)d_in[1];
    const float* ln1b  = (const float*)d_in[2];
    const float* ln2w  = (const float*)d_in[3];
    const float* ln2b  = (const float*)d_in[4];
    const float* w_qkv = (const float*)d_in[5];
    const float* b_qkv = (const float*)d_in[6];
    const float* w_out = (const float*)d_in[7];
    const float* b_out = (const float*)d_in[8];
    const float* w_rtr = (const float*)d_in[9];
    const float* wi    = (const float*)d_in[10];
    const float* wo    = (const float*)d_in[11];
    float* out = (float*)d_out;

    char* wsb = (char*)d_ws;
    __hip_bfloat16* wqH  = (__hip_bfloat16*)(wsb + OFF_WQH);
    __hip_bfloat16* wqL  = (__hip_bfloat16*)(wsb + OFF_WQL);
    __hip_bfloat16* woH  = (__hip_bfloat16*)(wsb + OFF_WOH);
    __hip_bfloat16* woL  = (__hip_bfloat16*)(wsb + OFF_WOL);
    __hip_bfloat16* h1H  = (__hip_bfloat16*)(wsb + OFF_H1H);
    __hip_bfloat16* h1L  = (__hip_bfloat16*)(wsb + OFF_H1L);
    float*          qkvF = (float*)(wsb + OFF_QKV);
    __hip_bfloat16* oH   = (__hip_bfloat16*)(wsb + OFF_OH);
    __hip_bfloat16* oL   = (__hip_bfloat16*)(wsb + OFF_OL);
    float*          x2F  = (float*)(wsb + OFF_X2);
    __hip_bfloat16* h2B  = (__hip_bfloat16*)(wsb + OFF_H2B);
    __hip_bfloat16* actB = (__hip_bfloat16*)(wsb + OFF_ACT);
    short* KSH = (short*)(wsb + OFF_KSH);
    short* KSL = (short*)(wsb + OFF_KSL);
    short* VTH = (short*)(wsb + OFF_VTH);
    short* VTL = (short*)(wsb + OFF_VTL);
    float* gate = (float*)(wsb + OFF_GATE);
    int* eid    = (int*)(wsb + OFF_EID);
    int* perm   = (int*)(wsb + OFF_PERM);
    int* counts = (int*)(wsb + OFF_CNT);
    int* fill   = (int*)(wsb + OFF_FILL);
    int* ntl    = (int*)(wsb + OFF_NT);
    int* te     = (int*)(wsb + OFF_TE);
    int* tsx    = (int*)(wsb + OFF_TS);
    int* trx    = (int*)(wsb + OFF_TR);
    int* te2    = (int*)(wsb + OFF_TE2);
    int* ts2    = (int*)(wsb + OFF_TS2);
    int* tr2    = (int*)(wsb + OFF_TR2);
    int* ntl2   = (int*)(wsb + OFF_NT2);

    k_phase0<<<6144, 256, 0, stream>>>(x, ln1w, ln1b, h1H, h1L, w_qkv, wqH, wqL,
                                       w_out, woH, woL);
    k_qkv<<<768, 256, 0, stream>>>(h1H, h1L, wqH, wqL, b_qkv, qkvF);
    k_prep<<<dim3(SS / 64, HH, BB), 256, 0, stream>>>(qkvF, KSH, KSL, VTH, VTL);
    k_attn_mfma<<<256, 512, 0, stream>>>(qkvF, KSH, KSL, VTH, VTL, oH, oL);
    k_oproj64<<<256, 256, 0, stream>>>(oH, oL, woH, woL, b_out, x, x2F, counts);
    k_ln2_router<<<MM, 256, 0, stream>>>(x2F, ln2w, ln2b, w_rtr, h2B,
                                         out + (size_t)MM * DD, gate, eid, counts);
    k_offscatter<<<1, 1024, 0, stream>>>(counts, te, tsx, trx, ntl,
                                         te2, ts2, tr2, ntl2, eid, fill, perm);
    k_moe_up<<<dim3(32, MAX_TILES), 256, 0, stream>>>(h2B, wi, actB, perm, te, tsx, trx, ntl);
    k_moe_dn<<<dim3(DD / 64, MAX_TILES2), 256, 0, stream>>>(
        actB, wo, x2F, out, perm, te2, ts2, tr2, ntl2, gate);
}

// Round 20
// 304.023 us; speedup vs baseline: 1.1675x; 1.1675x over previous
//
#include <hip/hip_runtime.h>
#include <hip/hip_bf16.h>
#include <math.h>

// Problem constants
#define BB 2
#define SS 1024
#define DD 1024
#define FF 4096
#define HH 16
#define EE 8
#define MM (BB*SS)          // 2048 tokens
#define MAX_TILES 24        // BM=128 tiles
#define MAX_TILES2 40       // BM=64 tiles

typedef __attribute__((ext_vector_type(8))) short bf16x8;
typedef __attribute__((ext_vector_type(8))) short s16x8;
typedef __attribute__((ext_vector_type(4))) float f32x4;

// ---------------- workspace layout (bytes) ----------------
#define OFF_WIT  ((size_t)0)            // wi^T bf16: 67108864
#define OFF_WOT  ((size_t)67108864)     // wo^T bf16: 33554432
#define OFF_WQH  ((size_t)100663296)    // w_qkv hi bf16 (later: K split hi/lo)
#define OFF_WQL  ((size_t)106954752)    // w_qkv lo bf16
#define OFF_WOH  ((size_t)113246208)    // w_out hi bf16
#define OFF_WOL  ((size_t)115343360)    // w_out lo bf16
#define OFF_H1H  ((size_t)117440512)    // h1 hi bf16 (later: VT hi)
#define OFF_H1L  ((size_t)121634816)    // h1 lo bf16 (later: VT lo)
#define OFF_QKV  ((size_t)125829120)    // qkv f32: 25165824
#define OFF_OH   ((size_t)150994944)    // attn o hi bf16
#define OFF_OL   ((size_t)155189248)    // attn o lo bf16
#define OFF_X2   ((size_t)159383552)    // x2 f32: 8388608
#define OFF_H2B  ((size_t)167772160)    // h2 bf16: 4194304
#define OFF_ACT  ((size_t)171966464)    // act bf16
#define OFF_GATE ((size_t)180879360)
#define OFF_EID  ((size_t)180887552)
#define OFF_PERM ((size_t)180895744)
#define OFF_CNT  ((size_t)180903936)    // 17 ints zeroed by out-proj block 0
#define OFF_FILL ((size_t)180903968)
#define OFF_NT   ((size_t)180904000)
#define OFF_TE   ((size_t)180904192)
#define OFF_TS   ((size_t)180904320)
#define OFF_TR   ((size_t)180904448)
#define OFF_TE2  ((size_t)180904576)
#define OFF_TS2  ((size_t)180904768)
#define OFF_TR2  ((size_t)180904960)
#define OFF_NT2  ((size_t)180905152)
// attention K/V split buffers (reuse dead regions)
#define OFF_KSH  OFF_WQH
#define OFF_KSL  (OFF_WQH + 4194304)
#define OFF_VTH  OFF_H1H
#define OFF_VTL  OFF_H1L

// ---------------- async global->LDS (16B per lane) ----------------
__device__ __forceinline__ void gload16(const void* g, void* l) {
    __builtin_amdgcn_global_load_lds(
        (const __attribute__((address_space(1))) unsigned int*)g,
        (__attribute__((address_space(3))) unsigned int*)l, 16, 0, 0);
}

__device__ __forceinline__ short bfh(float v) {
    __hip_bfloat16 h = __float2bfloat16(v);
    return *(short*)&h;
}
__device__ __forceinline__ float bf2f(short s) {
    __hip_bfloat16 h = *(__hip_bfloat16*)&s;
    return __bfloat162float(h);
}

__device__ __forceinline__ void split_write(float v, __hip_bfloat16* hp, __hip_bfloat16* lp, size_t idx) {
    __hip_bfloat16 h = __float2bfloat16(v);
    hp[idx] = h;
    lp[idx] = __float2bfloat16(v - __bfloat162float(h));
}

// ---------------- transpose-convert body (local thread id t in [0,256)) ----------------
__device__ __forceinline__ void tcvt64_body(const float* __restrict__ in, __hip_bfloat16* __restrict__ out,
                                            int R, int C, int r0, int c0, float* tile /*64*65*/, int t) {
    {
        int ri = t >> 2, cj = (t & 3) * 16;
        const float* ip = &in[(size_t)(r0 + ri) * C + c0 + cj];
#pragma unroll
        for (int k = 0; k < 4; ++k) {
            float4 v = *(const float4*)(ip + k * 4);
            tile[ri * 65 + cj + k * 4 + 0] = v.x;
            tile[ri * 65 + cj + k * 4 + 1] = v.y;
            tile[ri * 65 + cj + k * 4 + 2] = v.z;
            tile[ri * 65 + cj + k * 4 + 3] = v.w;
        }
    }
    __syncthreads();
    {
        int co = t >> 2, rj = (t & 3) * 16;
        bf16x8 v8a, v8b;
#pragma unroll
        for (int q = 0; q < 8; ++q) v8a[q] = bfh(tile[(rj + q) * 65 + co]);
#pragma unroll
        for (int q = 0; q < 8; ++q) v8b[q] = bfh(tile[(rj + 8 + q) * 65 + co]);
        __hip_bfloat16* op = &out[(size_t)(c0 + co) * R + r0 + rj];
        *(bf16x8*)op = v8a;
        *(bf16x8*)(op + 8) = v8b;
    }
}

// ---------------- phase-0: LN1+RoPE [0,2048) | w_qkv cvt [2048,5120) | w_out cvt [5120,6144) ----------
__global__ void k_phase0(const float* __restrict__ x, const float* __restrict__ ln1w,
                         const float* __restrict__ ln1b,
                         __hip_bfloat16* __restrict__ h1H, __hip_bfloat16* __restrict__ h1L,
                         const float* __restrict__ w_qkv, __hip_bfloat16* __restrict__ wqH,
                         __hip_bfloat16* __restrict__ wqL,
                         const float* __restrict__ w_out, __hip_bfloat16* __restrict__ woH,
                         __hip_bfloat16* __restrict__ woL) {
    __shared__ __align__(16) float smem[1032];
    int bid = blockIdx.x, t = threadIdx.x;
    if (bid < 2048) {
        int m = bid, s = m & (SS - 1);
        float* row = smem;
        float* red = smem + 1024;
        const float* xp = x + (size_t)m * DD;
        float sum = 0.f, sumsq = 0.f;
#pragma unroll
        for (int l = 0; l < 4; ++l) {
            int i = t + l * 256;
            float v = xp[i];
            row[i] = v;
            sum += v; sumsq += v * v;
        }
#pragma unroll
        for (int off = 32; off; off >>= 1) {
            sum   += __shfl_xor(sum, off);
            sumsq += __shfl_xor(sumsq, off);
        }
        int wid = t >> 6, lane = t & 63;
        if (lane == 0) { red[wid] = sum; red[4 + wid] = sumsq; }
        __syncthreads();
        sum   = red[0] + red[1] + red[2] + red[3];
        sumsq = red[4] + red[5] + red[6] + red[7];
        float mean = sum * (1.f / DD);
        float var  = sumsq * (1.f / DD) - mean * mean;
        float rstd = rsqrtf(var + 1e-5f);
        size_t base = (size_t)m * DD;
        const float kln = logf(10000.f) / 512.f;
#pragma unroll
        for (int l = 0; l < 2; ++l) {
            int i = t + l * 256;   // 0..511
            float n1 = (row[i]       - mean) * rstd * ln1w[i]       + ln1b[i];
            float n2 = (row[i + 512] - mean) * rstd * ln1w[i + 512] + ln1b[i + 512];
            float inv = expf(-(float)i * kln);
            float ang = (float)s * inv;
            float c = cosf(ang), sn = sinf(ang);
            split_write(n1 * c - n2 * sn,  h1H, h1L, base + i);
            split_write(n1 * sn + n2 * c, h1H, h1L, base + i + 512);
        }
    } else if (bid < 5120) {
        int idx = (bid - 2048) * 256 + t;        // 786432 float4
        float4 v = ((const float4*)w_qkv)[idx];
        split_write(v.x, wqH, wqL, (size_t)idx * 4 + 0);
        split_write(v.y, wqH, wqL, (size_t)idx * 4 + 1);
        split_write(v.z, wqH, wqL, (size_t)idx * 4 + 2);
        split_write(v.w, wqH, wqL, (size_t)idx * 4 + 3);
    } else {
        int idx = (bid - 5120) * 256 + t;        // 262144 float4
        float4 v = ((const float4*)w_out)[idx];
        split_write(v.x, woH, woL, (size_t)idx * 4 + 0);
        split_write(v.y, woH, woL, (size_t)idx * 4 + 1);
        split_write(v.z, woH, woL, (size_t)idx * 4 + 2);
        split_write(v.w, woH, woL, (size_t)idx * 4 + 3);
    }
}

// ---------------- qkv split GEMM, 64x128 tile, XCD-swizzled n-panels (768 blocks) ----------------
__global__ void k_qkv(const __hip_bfloat16* __restrict__ Ah, const __hip_bfloat16* __restrict__ Al,
                      const __hip_bfloat16* __restrict__ Bh, const __hip_bfloat16* __restrict__ Bl,
                      const float* __restrict__ bias, float* __restrict__ Cf) {
    __shared__ __align__(16) short AsH[64 * 32];
    __shared__ __align__(16) short AsL[64 * 32];
    __shared__ __align__(16) short BsH[128 * 32];
    __shared__ __align__(16) short BsL[128 * 32];
    const int N = 3072, K = DD;
    int bid = blockIdx.x;
    int xcd = bid & 7, idx = bid >> 3;
    int nt = xcd + (idx >> 5) * 8;
    int mt = idx & 31;
    int m0 = mt * 64, n0 = nt * 128;
    const int t = threadIdx.x;
    const int w = t >> 6, lane = t & 63;
    const int sid = w * 64 + lane;
    const int g = lane >> 4, r16 = lane & 15;

    f32x4 acc[4][2] = {};

    for (int k0 = 0; k0 < K; k0 += 32) {
        {
            int rrow = sid >> 2, sl = sid & 3;
            int slog = sl ^ ((rrow >> 1) & 3);
            size_t lbase = (size_t)(w * 64) * 8;
            size_t gaoff = (size_t)(m0 + rrow) * K + k0 + slog * 8;
            gload16(Ah + gaoff, &AsH[lbase]);
            gload16(Al + gaoff, &AsL[lbase]);
        }
#pragma unroll
        for (int j = 0; j < 2; ++j) {
            int id = j * 256 + sid;
            int rrow = id >> 2, sl = id & 3;
            int slog = sl ^ ((rrow >> 1) & 3);
            size_t lbase = (size_t)(j * 256 + w * 64) * 8;
            size_t gboff = (size_t)(n0 + rrow) * K + k0 + slog * 8;
            gload16(Bh + gboff, &BsH[lbase]);
            gload16(Bl + gboff, &BsL[lbase]);
        }
        __syncthreads();
        bf16x8 ah[4], al[4], bh[2], bl[2];
#pragma unroll
        for (int i = 0; i < 4; ++i) {
            int ra = i * 16 + r16;
            int pa = g ^ ((ra >> 1) & 3);
            ah[i] = *(const bf16x8*)&AsH[ra * 32 + pa * 8];
            al[i] = *(const bf16x8*)&AsL[ra * 32 + pa * 8];
        }
#pragma unroll
        for (int n = 0; n < 2; ++n) {
            int rb = w * 32 + n * 16 + r16;
            int pb = g ^ ((rb >> 1) & 3);
            bh[n] = *(const bf16x8*)&BsH[rb * 32 + pb * 8];
            bl[n] = *(const bf16x8*)&BsL[rb * 32 + pb * 8];
        }
#pragma unroll
        for (int i = 0; i < 4; ++i)
#pragma unroll
            for (int n = 0; n < 2; ++n) {
                acc[i][n] = __builtin_amdgcn_mfma_f32_16x16x32_bf16(ah[i], bh[n], acc[i][n], 0, 0, 0);
                acc[i][n] = __builtin_amdgcn_mfma_f32_16x16x32_bf16(ah[i], bl[n], acc[i][n], 0, 0, 0);
                acc[i][n] = __builtin_amdgcn_mfma_f32_16x16x32_bf16(al[i], bh[n], acc[i][n], 0, 0, 0);
            }
        __syncthreads();
    }

#pragma unroll
    for (int i = 0; i < 4; ++i) {
#pragma unroll
        for (int n = 0; n < 2; ++n) {
            int col = n0 + w * 32 + n * 16 + r16;
#pragma unroll
            for (int q = 0; q < 4; ++q) {
                int r = m0 + i * 16 + g * 4 + q;
                Cf[(size_t)r * N + col] = acc[i][n][q] + bias[col];
            }
        }
    }
}

// ---------------- out-proj split GEMM, 64x128 tile ----------------
__global__ void k_oproj64(const __hip_bfloat16* __restrict__ Ah, const __hip_bfloat16* __restrict__ Al,
                          const __hip_bfloat16* __restrict__ Bh, const __hip_bfloat16* __restrict__ Bl,
                          const float* __restrict__ bias, const float* __restrict__ addsrc,
                          float* __restrict__ Cf, int* __restrict__ zero17) {
    __shared__ __align__(16) short AsH[64 * 32];
    __shared__ __align__(16) short AsL[64 * 32];
    __shared__ __align__(16) short BsH[128 * 32];
    __shared__ __align__(16) short BsL[128 * 32];
    const int N = DD, K = DD;
    int bid = blockIdx.x;
    int m0 = (bid >> 3) * 64, n0 = (bid & 7) * 128;
    const int t = threadIdx.x;
    if (bid == 0 && t < 17) zero17[t] = 0;
    const int w = t >> 6, lane = t & 63;
    const int sid = w * 64 + lane;
    const int g = lane >> 4, r16 = lane & 15;

    f32x4 acc[4][2] = {};

    for (int k0 = 0; k0 < K; k0 += 32) {
        {
            int rrow = sid >> 2, sl = sid & 3;
            int slog = sl ^ ((rrow >> 1) & 3);
            size_t lbase = (size_t)(w * 64) * 8;
            size_t gaoff = (size_t)(m0 + rrow) * K + k0 + slog * 8;
            gload16(Ah + gaoff, &AsH[lbase]);
            gload16(Al + gaoff, &AsL[lbase]);
        }
#pragma unroll
        for (int j = 0; j < 2; ++j) {
            int id = j * 256 + sid;
            int rrow = id >> 2, sl = id & 3;
            int slog = sl ^ ((rrow >> 1) & 3);
            size_t lbase = (size_t)(j * 256 + w * 64) * 8;
            size_t gboff = (size_t)(n0 + rrow) * K + k0 + slog * 8;
            gload16(Bh + gboff, &BsH[lbase]);
            gload16(Bl + gboff, &BsL[lbase]);
        }
        __syncthreads();
        bf16x8 ah[4], al[4], bh[2], bl[2];
#pragma unroll
        for (int i = 0; i < 4; ++i) {
            int ra = i * 16 + r16;
            int pa = g ^ ((ra >> 1) & 3);
            ah[i] = *(const bf16x8*)&AsH[ra * 32 + pa * 8];
            al[i] = *(const bf16x8*)&AsL[ra * 32 + pa * 8];
        }
#pragma unroll
        for (int n = 0; n < 2; ++n) {
            int rb = w * 32 + n * 16 + r16;
            int pb = g ^ ((rb >> 1) & 3);
            bh[n] = *(const bf16x8*)&BsH[rb * 32 + pb * 8];
            bl[n] = *(const bf16x8*)&BsL[rb * 32 + pb * 8];
        }
#pragma unroll
        for (int i = 0; i < 4; ++i)
#pragma unroll
            for (int n = 0; n < 2; ++n) {
                acc[i][n] = __builtin_amdgcn_mfma_f32_16x16x32_bf16(ah[i], bh[n], acc[i][n], 0, 0, 0);
                acc[i][n] = __builtin_amdgcn_mfma_f32_16x16x32_bf16(ah[i], bl[n], acc[i][n], 0, 0, 0);
                acc[i][n] = __builtin_amdgcn_mfma_f32_16x16x32_bf16(al[i], bh[n], acc[i][n], 0, 0, 0);
            }
        __syncthreads();
    }

#pragma unroll
    for (int i = 0; i < 4; ++i) {
#pragma unroll
        for (int n = 0; n < 2; ++n) {
            int col = n0 + w * 32 + n * 16 + r16;
#pragma unroll
            for (int q = 0; q < 4; ++q) {
                int r = m0 + i * 16 + g * 4 + q;
                Cf[(size_t)r * N + col] =
                    acc[i][n][q] + bias[col] + addsrc[(size_t)r * N + col];
            }
        }
    }
}

// ---------------- MoE up-proj pure GEMM (interleaved a/g + silu epilogue) ----------------
__global__ void k_moe_up(const __hip_bfloat16* __restrict__ A,
                         const __hip_bfloat16* __restrict__ Bt,
                         __hip_bfloat16* __restrict__ act,
                         const int* __restrict__ perm,
                         const int* __restrict__ te, const int* __restrict__ ts,
                         const int* __restrict__ tr, const int* __restrict__ ntl) {
    __shared__ __align__(16) short As[128 * 32];
    __shared__ __align__(16) short Bs[128 * 32];
    __shared__ int permS[128];
    int tile = blockIdx.y;
    if (tile >= *ntl) return;
    int e = te[tile], rs = ts[tile], rows = tr[tile];
    const int t = threadIdx.x;
    if (t < 128) permS[t] = (t < rows) ? perm[rs + t] : 0;
    __syncthreads();
    int c0 = blockIdx.x * 64;
    const int w = t >> 6, lane = t & 63;
    const int wr = w >> 1, wc = w & 1;
    const int sid = w * 64 + lane;
    const int g = lane >> 4, r16 = lane & 15;

    const __hip_bfloat16* Bp = Bt + (size_t)e * FF * DD;

    f32x4 acc[4][4] = {};

    for (int k0 = 0; k0 < DD; k0 += 32) {
#pragma unroll
        for (int j = 0; j < 2; ++j) {
            int id = j * 256 + sid;
            int rrow = id >> 2, sl = id & 3;
            int slog = sl ^ ((rrow >> 1) & 3);
            size_t lbase = (size_t)(j * 256 + w * 64) * 8;
            gload16(A + (size_t)permS[rrow] * DD + k0 + slog * 8, &As[lbase]);
            int q = rrow >> 4, rr = rrow & 15;
            int wrow = c0 + (q >> 2) * 32 + ((q & 3) >> 1) * 16 + rr + (q & 1) * 2048;
            gload16(Bp + (size_t)wrow * DD + k0 + slog * 8, &Bs[lbase]);
        }
        __syncthreads();
        bf16x8 af[4], bfr[4];
#pragma unroll
        for (int i = 0; i < 4; ++i) {
            int ra = wr * 64 + i * 16 + r16;
            int pa = g ^ ((ra >> 1) & 3);
            af[i] = *(const bf16x8*)&As[ra * 32 + pa * 8];
            int rb = wc * 64 + i * 16 + r16;
            int pb = g ^ ((rb >> 1) & 3);
            bfr[i] = *(const bf16x8*)&Bs[rb * 32 + pb * 8];
        }
#pragma unroll
        for (int i = 0; i < 4; ++i)
#pragma unroll
            for (int n = 0; n < 4; ++n)
                acc[i][n] = __builtin_amdgcn_mfma_f32_16x16x32_bf16(af[i], bfr[n], acc[i][n], 0, 0, 0);
        __syncthreads();
    }

#pragma unroll
    for (int i = 0; i < 4; ++i) {
#pragma unroll
        for (int p2 = 0; p2 < 2; ++p2) {
            int col = c0 + wc * 32 + p2 * 16 + r16;
#pragma unroll
            for (int q = 0; q < 4; ++q) {
                int r = wr * 64 + i * 16 + g * 4 + q;
                if (r < rows) {
                    float a  = acc[i][2 * p2][q];
                    float gv = acc[i][2 * p2 + 1][q];
                    act[(size_t)(rs + r) * 2048 + col] =
                        __float2bfloat16((a / (1.f + expf(-a))) * gv);
                }
            }
        }
    }
}

// ---------------- MoE down-proj, 64x128 tile (BM=64 tile list) ----------------
__global__ void k_moe_dn(const __hip_bfloat16* __restrict__ A,
                         const __hip_bfloat16* __restrict__ Bt,
                         const float* __restrict__ addsrc, float* __restrict__ Cf,
                         const int* __restrict__ perm,
                         const int* __restrict__ te2, const int* __restrict__ ts2,
                         const int* __restrict__ tr2, const int* __restrict__ ntl2,
                         const float* __restrict__ gate) {
    __shared__ __align__(16) short As[64 * 32];
    __shared__ __align__(16) short Bs[128 * 32];
    __shared__ int permS[64];
    int tile = blockIdx.y;
    if (tile >= *ntl2) return;
    int e = te2[tile], rs = ts2[tile], rows = tr2[tile];
    const int t = threadIdx.x;
    if (t < 64) permS[t] = (t < rows) ? perm[rs + t] : 0;
    __syncthreads();
    int n0 = blockIdx.x * 128;
    const int w = t >> 6, lane = t & 63;
    const int sid = w * 64 + lane;
    const int g = lane >> 4, r16 = lane & 15;
    const int K = FF / 2;

    const __hip_bfloat16* Bp = Bt + (size_t)e * DD * (FF / 2);

    f32x4 acc[4][2] = {};

    for (int k0 = 0; k0 < K; k0 += 32) {
        {
            int rrow = sid >> 2, sl = sid & 3;
            int slog = sl ^ ((rrow >> 1) & 3);
            size_t lbase = (size_t)(w * 64) * 8;
            gload16(A + (size_t)(rs + rrow) * K + k0 + slog * 8, &As[lbase]);
        }
#pragma unroll
        for (int j = 0; j < 2; ++j) {
            int id = j * 256 + sid;
            int rrow = id >> 2, sl = id & 3;
            int slog = sl ^ ((rrow >> 1) & 3);
            size_t lbase = (size_t)(j * 256 + w * 64) * 8;
            gload16(Bp + (size_t)(n0 + rrow) * K + k0 + slog * 8, &Bs[lbase]);
        }
        __syncthreads();
        bf16x8 af[4], bfr[2];
#pragma unroll
        for (int i = 0; i < 4; ++i) {
            int ra = i * 16 + r16;
            int pa = g ^ ((ra >> 1) & 3);
            af[i] = *(const bf16x8*)&As[ra * 32 + pa * 8];
        }
#pragma unroll
        for (int n = 0; n < 2; ++n) {
            int rb = w * 32 + n * 16 + r16;
            int pb = g ^ ((rb >> 1) & 3);
            bfr[n] = *(const bf16x8*)&Bs[rb * 32 + pb * 8];
        }
#pragma unroll
        for (int i = 0; i < 4; ++i)
#pragma unroll
            for (int n = 0; n < 2; ++n)
                acc[i][n] = __builtin_amdgcn_mfma_f32_16x16x32_bf16(af[i], bfr[n], acc[i][n], 0, 0, 0);
        __syncthreads();
    }

#pragma unroll
    for (int i = 0; i < 4; ++i) {
#pragma unroll
        for (int n = 0; n < 2; ++n) {
            int col = n0 + w * 32 + n * 16 + r16;
#pragma unroll
            for (int q = 0; q < 4; ++q) {
                int r = i * 16 + g * 4 + q;
                if (r >= rows) continue;
                int tok = permS[r];
                Cf[(size_t)tok * DD + col] = addsrc[(size_t)tok * DD + col] + gate[tok] * acc[i][n][q];
            }
        }
    }
}

// ---------------- attention prep: split K -> [b,h,s,d] swz, V^T -> [b,h,d,s] swz ----------------
__global__ void k_prep(const float* __restrict__ qkv, short* __restrict__ KH, short* __restrict__ KL,
                       short* __restrict__ VH, short* __restrict__ VL) {
    __shared__ float tile[64][65];
    int b = blockIdx.z, h = blockIdx.y, s0 = blockIdx.x * 64;
    int t = threadIdx.x;
    int row = t >> 2, c0 = (t & 3) * 16;
    const float* kp = qkv + (size_t)(b * SS + s0 + row) * 3072 + 1024 + h * 64 + c0;
    const float* vp = kp + 1024;
    {
        size_t krow = ((size_t)(b * HH + h) * SS + s0 + row) * 64;
        int key = (s0 + row) & 7;
#pragma unroll
        for (int g2 = 0; g2 < 2; ++g2) {
            s16x8 hv, lv;
#pragma unroll
            for (int j = 0; j < 8; ++j) {
                float v = kp[g2 * 8 + j];
                short hh = bfh(v);
                hv[j] = hh; lv[j] = bfh(v - bf2f(hh));
            }
            int p = ((c0 >> 3) + g2) ^ key;
            *(s16x8*)&KH[krow + p * 8] = hv;
            *(s16x8*)&KL[krow + p * 8] = lv;
        }
    }
#pragma unroll
    for (int j = 0; j < 16; ++j) tile[row][c0 + j] = vp[j];
    __syncthreads();
    {
        int d = t >> 2, sc = (t & 3) * 16;
        size_t vrow = ((size_t)(b * HH + h) * 64 + d) * SS + s0;
        int key = d & 7;
#pragma unroll
        for (int g2 = 0; g2 < 2; ++g2) {
            s16x8 hv, lv;
#pragma unroll
            for (int j = 0; j < 8; ++j) {
                float v = tile[sc + g2 * 8 + j][d];
                short hh = bfh(v);
                hv[j] = hh; lv[j] = bfh(v - bf2f(hh));
            }
            int p = ((sc >> 3) + g2) ^ key;
            *(s16x8*)&VH[vrow + p * 8] = hv;
            *(s16x8*)&VL[vrow + p * 8] = lv;
        }
    }
}

// ---------------- attention mega: attn [0,256) | wi tcvt [256,4352) | wo tcvt [4352,6400) ----------
// Attention: single-buffer K/V, 8 waves x 16 q-rows, XCD-swizzled. 69632B LDS -> 2 blocks/CU,
// so one attn block + one tcvt streamer co-reside per CU (MFMA pipe + memory pipe overlap).
#define LDP 72
__global__ __launch_bounds__(512, 4)
void k_attn_mega(const float* __restrict__ qkv,
                 const short* __restrict__ KH, const short* __restrict__ KL,
                 const short* __restrict__ VH, const short* __restrict__ VL,
                 __hip_bfloat16* __restrict__ ohi, __hip_bfloat16* __restrict__ olo,
                 const float* __restrict__ wi, __hip_bfloat16* __restrict__ wiT,
                 const float* __restrict__ wo, __hip_bfloat16* __restrict__ woT) {
    __shared__ __align__(16) char smem[69632];
    int id = blockIdx.x;
    if (id >= 256) {
        // ---- tcvt streamers: 512 threads, 2 tiles per block
        int t512 = threadIdx.x;
        int half = t512 >> 8, t = t512 & 255;
        float* tile = (float*)(smem + half * 16640);
        if (id < 4352) {
            int gidx = (id - 256) * 2 + half;      // [0, 8192)
            int e = gidx >> 10, rem = gidx & 1023;
            int ry = rem >> 6, cx = rem & 63;
            tcvt64_body(wi + (size_t)e * DD * FF, wiT + (size_t)e * DD * FF,
                        1024, 4096, ry * 64, cx * 64, tile, t);
        } else {
            int gidx = (id - 4352) * 2 + half;     // [0, 4096)
            int e = gidx >> 9, rem = gidx & 511;
            int ry = rem >> 4, cx = rem & 15;
            tcvt64_body(wo + (size_t)e * 2048 * 1024, woT + (size_t)e * 2048 * 1024,
                        2048, 1024, ry * 64, cx * 64, tile, t);
        }
        return;
    }
    short* Ks  = (short*)smem;                    // 8192B
    short* Kl2 = (short*)(smem + 8192);
    short* Vs  = (short*)(smem + 16384);
    short* Vl2 = (short*)(smem + 24576);
    int xcd = id & 7, slot = id >> 3;
    int bh = xcd * 4 + (slot >> 3);
    int q0 = (slot & 7) * 128;
    int b = bh >> 4, h = bh & 15;
    int t = threadIdx.x;
    int w = t >> 6, lane = t & 63;
    int g = lane >> 4, r16 = lane & 15;
    int srow = t >> 3, sslot = t & 7;
    short* PhS = (short*)(smem + 32768 + w * 2304);
    short* PlS = (short*)(smem + 51200 + w * 2304);

    const size_t kbase = ((size_t)bh * SS) * 64;
    const size_t vbase = ((size_t)bh * 64) * SS;

    bf16x8 qfh[2], qfl[2];
    {
        const float* qp = qkv + (size_t)(b * SS + q0 + w * 16 + r16) * 3072 + h * 64;
#pragma unroll
        for (int ks = 0; ks < 2; ++ks) {
            float vv[8];
            *(float4*)&vv[0] = *(const float4*)(qp + ks * 32 + g * 8);
            *(float4*)&vv[4] = *(const float4*)(qp + ks * 32 + g * 8 + 4);
#pragma unroll
            for (int j = 0; j < 8; ++j) {
                float sv = vv[j] * 0.125f;
                short hh = bfh(sv);
                qfh[ks][j] = hh;
                qfl[ks][j] = bfh(sv - bf2f(hh));
            }
        }
    }

    float mrun[4], lrun[4];
    f32x4 oacc[4] = {};
#pragma unroll
    for (int q = 0; q < 4; ++q) { mrun[q] = -1e30f; lrun[q] = 0.f; }

    for (int k0 = 0; k0 < SS; k0 += 64) {
        gload16(KH + kbase + (size_t)(k0 + srow) * 64 + sslot * 8, Ks  + w * 512);
        gload16(KL + kbase + (size_t)(k0 + srow) * 64 + sslot * 8, Kl2 + w * 512);
        gload16(VH + vbase + (size_t)srow * SS + k0 + sslot * 8,   Vs  + w * 512);
        gload16(VL + vbase + (size_t)srow * SS + k0 + sslot * 8,   Vl2 + w * 512);
        __syncthreads();

        f32x4 accs[4] = {};
#pragma unroll
        for (int ks = 0; ks < 2; ++ks) {
            bf16x8 kfh[4], kfl[4];
#pragma unroll
            for (int n = 0; n < 4; ++n) {
                int rb = n * 16 + r16;
                int p = (ks * 4 + g) ^ (r16 & 7);
                kfh[n] = *(const bf16x8*)&Ks[rb * 64 + p * 8];
                kfl[n] = *(const bf16x8*)&Kl2[rb * 64 + p * 8];
            }
            __builtin_amdgcn_s_setprio(1);
#pragma unroll
            for (int n = 0; n < 4; ++n) {
                accs[n] = __builtin_amdgcn_mfma_f32_16x16x32_bf16(qfh[ks], kfh[n], accs[n], 0, 0, 0);
                accs[n] = __builtin_amdgcn_mfma_f32_16x16x32_bf16(qfh[ks], kfl[n], accs[n], 0, 0, 0);
                accs[n] = __builtin_amdgcn_mfma_f32_16x16x32_bf16(qfl[ks], kfh[n], accs[n], 0, 0, 0);
            }
            __builtin_amdgcn_s_setprio(0);
        }

        float mn[4], corr[4], psum[4];
#pragma unroll
        for (int q = 0; q < 4; ++q) {
            float m = fmaxf(fmaxf(accs[0][q], accs[1][q]), fmaxf(accs[2][q], accs[3][q]));
            m = fmaxf(m, __shfl_xor(m, 1));
            m = fmaxf(m, __shfl_xor(m, 2));
            m = fmaxf(m, __shfl_xor(m, 4));
            m = fmaxf(m, __shfl_xor(m, 8));
            mn[q] = fmaxf(mrun[q], m);
            corr[q] = expf(mrun[q] - mn[q]);
            mrun[q] = mn[q];
            psum[q] = 0.f;
        }
#pragma unroll
        for (int n = 0; n < 4; ++n)
#pragma unroll
            for (int q = 0; q < 4; ++q) {
                float p = expf(accs[n][q] - mn[q]);
                psum[q] += p;
                short ph = bfh(p);
                PhS[(g * 4 + q) * LDP + n * 16 + r16] = ph;
                PlS[(g * 4 + q) * LDP + n * 16 + r16] = bfh(p - bf2f(ph));
            }
#pragma unroll
        for (int q = 0; q < 4; ++q) {
            psum[q] += __shfl_xor(psum[q], 1);
            psum[q] += __shfl_xor(psum[q], 2);
            psum[q] += __shfl_xor(psum[q], 4);
            psum[q] += __shfl_xor(psum[q], 8);
            lrun[q] = lrun[q] * corr[q] + psum[q];
#pragma unroll
            for (int n = 0; n < 4; ++n) oacc[n][q] *= corr[q];
        }

#pragma unroll
        for (int ks = 0; ks < 2; ++ks) {
            bf16x8 vfh[4], vfl[4];
#pragma unroll
            for (int n = 0; n < 4; ++n) {
                int rb = n * 16 + r16;
                int p = (ks * 4 + g) ^ (r16 & 7);
                vfh[n] = *(const bf16x8*)&Vs[rb * 64 + p * 8];
                vfl[n] = *(const bf16x8*)&Vl2[rb * 64 + p * 8];
            }
            bf16x8 pfh = *(const bf16x8*)&PhS[r16 * LDP + ks * 32 + g * 8];
            bf16x8 pfl = *(const bf16x8*)&PlS[r16 * LDP + ks * 32 + g * 8];
            __builtin_amdgcn_s_setprio(1);
#pragma unroll
            for (int n = 0; n < 4; ++n) {
                oacc[n] = __builtin_amdgcn_mfma_f32_16x16x32_bf16(pfh, vfh[n], oacc[n], 0, 0, 0);
                oacc[n] = __builtin_amdgcn_mfma_f32_16x16x32_bf16(pfh, vfl[n], oacc[n], 0, 0, 0);
                oacc[n] = __builtin_amdgcn_mfma_f32_16x16x32_bf16(pfl, vfh[n], oacc[n], 0, 0, 0);
            }
            __builtin_amdgcn_s_setprio(0);
        }
        __syncthreads();
    }

    float invl[4];
#pragma unroll
    for (int q = 0; q < 4; ++q) invl[q] = 1.f / lrun[q];
#pragma unroll
    for (int n = 0; n < 4; ++n) {
        int col = h * 64 + n * 16 + r16;
#pragma unroll
        for (int q = 0; q < 4; ++q) {
            int rowg = b * SS + q0 + w * 16 + g * 4 + q;
            split_write(oacc[n][q] * invl[q], ohi, olo, (size_t)rowg * DD + col);
        }
    }
}

// ---------------- fused LN2 + router ----------------
__global__ void k_ln2_router(const float* __restrict__ x2, const float* __restrict__ w,
                             const float* __restrict__ b, const float* __restrict__ wr,
                             __hip_bfloat16* __restrict__ h2b, float* __restrict__ logits,
                             float* __restrict__ gate, int* __restrict__ eid,
                             int* __restrict__ counts) {
    int m = blockIdx.x, t = threadIdx.x;
    __shared__ float red[8];
    __shared__ float racc[4][8];
    const float* xp = x2 + (size_t)m * DD;
    float v[4];
    float sum = 0.f, sumsq = 0.f;
#pragma unroll
    for (int l = 0; l < 4; ++l) {
        v[l] = xp[t + l * 256];
        sum += v[l]; sumsq += v[l] * v[l];
    }
#pragma unroll
    for (int off = 32; off; off >>= 1) {
        sum   += __shfl_xor(sum, off);
        sumsq += __shfl_xor(sumsq, off);
    }
    int wid = t >> 6, lane = t & 63;
    if (lane == 0) { red[wid] = sum; red[4 + wid] = sumsq; }
    __syncthreads();
    sum   = red[0] + red[1] + red[2] + red[3];
    sumsq = red[4] + red[5] + red[6] + red[7];
    float mean = sum * (1.f / DD);
    float var  = sumsq * (1.f / DD) - mean * mean;
    float rstd = rsqrtf(var + 1e-5f);
    float acc[EE] = {};
#pragma unroll
    for (int l = 0; l < 4; ++l) {
        int i = t + l * 256;
        float hv = (v[l] - mean) * rstd * w[i] + b[i];
        h2b[(size_t)m * DD + i] = __float2bfloat16(hv);
        const float* wp = wr + (size_t)i * EE;
#pragma unroll
        for (int n = 0; n < EE; ++n) acc[n] += hv * wp[n];
    }
#pragma unroll
    for (int off = 32; off; off >>= 1)
#pragma unroll
        for (int n = 0; n < EE; ++n) acc[n] += __shfl_xor(acc[n], off);
    if (lane == 0)
#pragma unroll
        for (int n = 0; n < EE; ++n) racc[wid][n] = acc[n];
    __syncthreads();
    if (t == 0) {
        float lg[EE];
#pragma unroll
        for (int n = 0; n < EE; ++n) lg[n] = racc[0][n] + racc[1][n] + racc[2][n] + racc[3][n];
        float mx = lg[0]; int best = 0;
#pragma unroll
        for (int n = 1; n < EE; ++n) if (lg[n] > mx) { mx = lg[n]; best = n; }
        float den = 0.f;
#pragma unroll
        for (int n = 0; n < EE; ++n) den += expf(lg[n] - mx);
        gate[m] = 1.f / den;
        eid[m] = best;
        atomicAdd(&counts[best], 1);
#pragma unroll
        for (int n = 0; n < EE; ++n) logits[(size_t)m * EE + n] = lg[n];
    }
}

// ---------------- fused routing bookkeeping: offsets + dual tile lists + scatter ----------------
__global__ void k_offscatter(const int* __restrict__ counts,
                             int* __restrict__ te, int* __restrict__ ts, int* __restrict__ tr,
                             int* __restrict__ ntl,
                             int* __restrict__ te2, int* __restrict__ ts2, int* __restrict__ tr2,
                             int* __restrict__ ntl2,
                             const int* __restrict__ eid,
                             int* __restrict__ fill, int* __restrict__ perm) {
    __shared__ int soffs[EE];
    int t = threadIdx.x;
    if (t == 0) {
        int off = 0, nt = 0, nt2 = 0;
        for (int e = 0; e < EE; ++e) {
            soffs[e] = off;
            int c = counts[e];
            for (int t0 = 0; t0 < c; t0 += 128) {
                te[nt] = e; ts[nt] = off + t0; tr[nt] = (c - t0 < 128) ? (c - t0) : 128; ++nt;
            }
            for (int t0 = 0; t0 < c; t0 += 64) {
                te2[nt2] = e; ts2[nt2] = off + t0; tr2[nt2] = (c - t0 < 64) ? (c - t0) : 64; ++nt2;
            }
            off += c;
        }
        *ntl = nt;
        *ntl2 = nt2;
    }
    __syncthreads();
#pragma unroll
    for (int tok = t; tok < MM; tok += 1024) {
        int e = eid[tok];
        int pos = soffs[e] + atomicAdd(&fill[e], 1);
        perm[pos] = tok;
    }
}

// ---------------- launch ----------------
extern "C" void kernel_launch(void* const* d_in, const int* in_sizes, int n_in,
                              void* d_out, int out_size, void* d_ws, size_t ws_size,
                              hipStream_t stream) {
    const float* x     = (const float*)d_in[0];
    const float* ln1w  = (const float*)d_in[1];
    const float* ln1b  = (const float*)d_in[2];
    const float* ln2w  = (const float*)d_in[3];
    const float* ln2b  = (const float*)d_in[4];
    const float* w_qkv = (const float*)d_in[5];
    const float* b_qkv = (const float*)d_in[6];
    const float* w_out = (const float*)d_in[7];
    const float* b_out = (const float*)d_in[8];
    const float* w_rtr = (const float*)d_in[9];
    const float* wi    = (const float*)d_in[10];
    const float* wo    = (const float*)d_in[11];
    float* out = (float*)d_out;

    char* wsb = (char*)d_ws;
    __hip_bfloat16* wiT  = (__hip_bfloat16*)(wsb + OFF_WIT);
    __hip_bfloat16* woT  = (__hip_bfloat16*)(wsb + OFF_WOT);
    __hip_bfloat16* wqH  = (__hip_bfloat16*)(wsb + OFF_WQH);
    __hip_bfloat16* wqL  = (__hip_bfloat16*)(wsb + OFF_WQL);
    __hip_bfloat16* woH  = (__hip_bfloat16*)(wsb + OFF_WOH);
    __hip_bfloat16* woL  = (__hip_bfloat16*)(wsb + OFF_WOL);
    __hip_bfloat16* h1H  = (__hip_bfloat16*)(wsb + OFF_H1H);
    __hip_bfloat16* h1L  = (__hip_bfloat16*)(wsb + OFF_H1L);
    float*          qkvF = (float*)(wsb + OFF_QKV);
    __hip_bfloat16* oH   = (__hip_bfloat16*)(wsb + OFF_OH);
    __hip_bfloat16* oL   = (__hip_bfloat16*)(wsb + OFF_OL);
    float*          x2F  = (float*)(wsb + OFF_X2);
    __hip_bfloat16* h2B  = (__hip_bfloat16*)(wsb + OFF_H2B);
    __hip_bfloat16* actB = (__hip_bfloat16*)(wsb + OFF_ACT);
    short* KSH = (short*)(wsb + OFF_KSH);
    short* KSL = (short*)(wsb + OFF_KSL);
    short* VTH = (short*)(wsb + OFF_VTH);
    short* VTL = (short*)(wsb + OFF_VTL);
    float* gate = (float*)(wsb + OFF_GATE);
    int* eid    = (int*)(wsb + OFF_EID);
    int* perm   = (int*)(wsb + OFF_PERM);
    int* counts = (int*)(wsb + OFF_CNT);
    int* fill   = (int*)(wsb + OFF_FILL);
    int* ntl    = (int*)(wsb + OFF_NT);
    int* te     = (int*)(wsb + OFF_TE);
    int* tsx    = (int*)(wsb + OFF_TS);
    int* trx    = (int*)(wsb + OFF_TR);
    int* te2    = (int*)(wsb + OFF_TE2);
    int* ts2    = (int*)(wsb + OFF_TS2);
    int* tr2    = (int*)(wsb + OFF_TR2);
    int* ntl2   = (int*)(wsb + OFF_NT2);

    // 1. phase-0: LN1+RoPE + w_qkv cvt + w_out cvt
    k_phase0<<<6144, 256, 0, stream>>>(x, ln1w, ln1b, h1H, h1L, w_qkv, wqH, wqL,
                                       w_out, woH, woL);
    // 2. qkv split GEMM (pure, XCD-swizzled, 768 blocks)
    k_qkv<<<768, 256, 0, stream>>>(h1H, h1L, wqH, wqL, b_qkv, qkvF);
    // 3. prep: split K + transposed V
    k_prep<<<dim3(SS / 64, HH, BB), 256, 0, stream>>>(qkvF, KSH, KSL, VTH, VTL);
    // 4. attention mega: attn (256) + wi/wo tcvt streamers co-resident (2 blocks/CU)
    k_attn_mega<<<6400, 512, 0, stream>>>(qkvF, KSH, KSL, VTH, VTL, oH, oL,
                                          wi, wiT, wo, woT);
    // 5. x2 = x + o @ w_out^T + b_out; zeroes routing counters
    k_oproj64<<<256, 256, 0, stream>>>(oH, oL, woH, woL, b_out, x, x2F, counts);
    // 6. LN2 + router fused
    k_ln2_router<<<MM, 256, 0, stream>>>(x2F, ln2w, ln2b, w_rtr, h2B,
                                         out + (size_t)MM * DD, gate, eid, counts);
    // 7. offsets + dual tile lists + scatter
    k_offscatter<<<1, 1024, 0, stream>>>(counts, te, tsx, trx, ntl,
                                         te2, ts2, tr2, ntl2, eid, fill, perm);
    // 8. moe_up pure GEMM (wiT bf16)
    k_moe_up<<<dim3(32, MAX_TILES), 256, 0, stream>>>(h2B, wiT, actB, perm, te, tsx, trx, ntl);
    // 9. moe_dn (woT bf16, BM=64 list)
    k_moe_dn<<<dim3(DD / 128, MAX_TILES2), 256, 0, stream>>>(
        actB, woT, x2F, out, perm, te2, ts2, tr2, ntl2, gate);
}